// Round 13
// baseline (1264.793 us; speedup 1.0000x reference)
//
#include <hip/hip_runtime.h>
#include <hip/hip_bf16.h>

#define B_   8
#define S_   32
#define N_   1024
#define H_   128
#define NH_  131072u    // N_*H_

typedef float f32;
typedef _Float16 f16;
typedef _Float16 half8 __attribute__((ext_vector_type(8)));
typedef float f32x4 __attribute__((ext_vector_type(4)));
typedef float f32x16 __attribute__((ext_vector_type(16)));

__device__ __forceinline__ float sig_fast(float x){
    return __builtin_amdgcn_rcpf(1.0f + __expf(-x));
}
__device__ __forceinline__ float tanh_fast(float x){
    return 1.0f - 2.0f*__builtin_amdgcn_rcpf(1.0f + __expf(2.0f*x));
}

// ---------------- weight prep + x transpose (merged) ----------------
__global__ void kprep(const f32* __restrict__ adj, const f32* __restrict__ x,
                      const f32* __restrict__ W1, const f32* __restrict__ b1,
                      const f32* __restrict__ W2, const f32* __restrict__ b2,
                      const f32* __restrict__ Wih, const f32* __restrict__ Whh,
                      const f32* __restrict__ bih, const f32* __restrict__ bhh,
                      f16* __restrict__ adj16, f16* __restrict__ XrT,
                      f16* __restrict__ WzX16, f16* __restrict__ Whh16,
                      f32* __restrict__ WihT, f32* __restrict__ bias512,
                      f32* __restrict__ biasP)
{
    int i = blockIdx.x*blockDim.x + threadIdx.x;
    if(i < 1048576){
        adj16[i] = (f16)adj[i];
        int m = i & 1023, q = i >> 10;
        int f = q & 3, b = (q>>2)&7, t = q>>5;
        XrT[i] = (f16)x[((b*32+t)<<12) + (m<<2) + f];
    }
    if(i < 81920){
        int j = i/160, k = i - j*160;
        float v;
        if(k < 128)      v = (j<384) ? W1[(4+k)*384 + j] : W2[(4+k)*128 + (j-384)];
        else if(k < 132) v = (j<384) ? W1[(k-128)*384 + j] : W2[(k-128)*128 + (j-384)];
        else             v = 0.f;
        WzX16[i] = (f16)v;
    }
    if(i < 65536){
        Whh16[i] = (f16)Whh[i];
        int k = i>>9, jj = i&511;
        WihT[i] = Wih[jj*128 + k];
    }
    if(i < 512){
        bias512[i] = (i<384) ? b1[i] : b2[i-384];
        biasP[i]   = bih[i] + bhh[i];
    }
}

// ---------------- AXP GEMM (runs once): C(1024x1024) = adj16 @ XrT^T, flat f16 out ----------------
__global__ __launch_bounds__(256, 4)
void kbigAXP(const f16* __restrict__ A, const f16* __restrict__ Bt, f16* __restrict__ C)
{
    const int lane = threadIdx.x & 63;
    const int w = threadIdx.x >> 6;          // k-quarter
    const int row0 = blockIdx.y*32, col0 = blockIdx.x*32;

    const int mr = row0 + (lane & 31);
    const int nc = col0 + (lane & 31);
    const int kb = w*256 + (lane>>5)*8;
    const f16* Ap = A  + (size_t)mr*1024 + kb;
    const f16* Bp = Bt + (size_t)nc*1024 + kb;

    half8 Ab[8], Bb[8];
    #pragma unroll
    for(int i=0;i<8;i++){
        Ab[i] = *(const half8*)(Ap + i*16);
        Bb[i] = *(const half8*)(Bp + i*16);
    }
    f32x16 acc0 = {}, acc1 = {};
    #pragma unroll
    for(int it=0; it<16; ++it){
        half8 av = Ab[it&7], bv = Bb[it&7];
        if(it < 8){
            Ab[it] = *(const half8*)(Ap + (it+8)*16);
            Bb[it] = *(const half8*)(Bp + (it+8)*16);
        }
        if(it & 1) acc1 = __builtin_amdgcn_mfma_f32_32x32x16_f16(av, bv, acc1, 0,0,0);
        else       acc0 = __builtin_amdgcn_mfma_f32_32x32x16_f16(av, bv, acc0, 0,0,0);
    }
    f32x16 acc = acc0 + acc1;

    __shared__ float red[3][32][32];
    if(w > 0){
        #pragma unroll
        for(int i=0;i<16;i++){
            int r = (i&3) + 8*(i>>2) + 4*(lane>>5);
            red[w-1][r][lane&31] = acc[i];
        }
    }
    __syncthreads();
    if(w == 0){
        #pragma unroll
        for(int i=0;i<16;i++){
            int r = (i&3) + 8*(i>>2) + 4*(lane>>5);
            int c = lane & 31;
            float v = acc[i] + red[0][r][c] + red[1][r][c] + red[2][r][c];
            C[(size_t)(row0 + r)*1024 + col0 + c] = (f16)v;
        }
    }
}

// ---------------- fused encoder step v5: 512 blocks x 512 thr, 2 blocks/CU ----------------
// Block = (b = bid&7, 16-node group g = bid>>3, m0 = g*16). bid%8==b -> XCD b.
// Z tile: 16 rows x 128 cols (b-slice), K=1024. 8 waves = col-quarter q (w&3, 32 cols)
//   x K-half kh (w>>2, 512). Wave: 16 chunks x 2 col-frags, 16x16x32 MFMA, depth-4 prefetch.
//   kh=1 -> red LDS; kh=0 adds -> Zs f16 [16][160] (ax cols 128..131, pad 132..159).
// act: 8 waves x 64 cols, K=160 -> global act (sig/tanh applied).
__global__ __launch_bounds__(512)
void kfz(const f16* __restrict__ adj16, const f16* __restrict__ hidT,
         const f16* __restrict__ WzX16, const f16* __restrict__ AXP16,
         const f32* __restrict__ bias512, f32* __restrict__ act, int t)
{
    const int tid = threadIdx.x;
    const int lane = tid & 63;
    const int w = tid >> 6;
    const int q = w & 3, kh = w >> 2;
    const int b = blockIdx.x & 7;
    const int m0 = (blockIdx.x >> 3) * 16;
    const int lr = lane & 15, kc = lane >> 4;

    __shared__ float red[4][16][32];   // 8 KB
    __shared__ f16 Zs[16][160];        // 5 KB

    {   // ---- Z phase ----
        f32x4 acc0 = {}, acc1 = {};
        if(t > 0){
            const f16* Ap  = adj16 + (size_t)(m0 + lr)*1024 + kh*512 + kc*8;
            const f16* Bp0 = hidT  + (size_t)(b*128 + q*32 + lr)*1024      + kh*512 + kc*8;
            const f16* Bp1 = Bp0 + 16*1024;

            half8 Ab[4], B0[4], B1[4];
            #pragma unroll
            for(int i=0;i<4;i++){
                Ab[i] = *(const half8*)(Ap  + i*32);
                B0[i] = *(const half8*)(Bp0 + i*32);
                B1[i] = *(const half8*)(Bp1 + i*32);
            }
            #pragma unroll
            for(int it=0; it<16; ++it){
                half8 av = Ab[it&3], b0 = B0[it&3], b1 = B1[it&3];
                if(it < 12){
                    Ab[it&3] = *(const half8*)(Ap  + (it+4)*32);
                    B0[it&3] = *(const half8*)(Bp0 + (it+4)*32);
                    B1[it&3] = *(const half8*)(Bp1 + (it+4)*32);
                }
                acc0 = __builtin_amdgcn_mfma_f32_16x16x32_f16(av, b0, acc0, 0,0,0);
                acc1 = __builtin_amdgcn_mfma_f32_16x16x32_f16(av, b1, acc1, 0,0,0);
            }
        }

        if(kh == 1){
            // C layout: col = lane&15, row = kc*4 + i
            #pragma unroll
            for(int i=0;i<4;i++){
                red[q][kc*4+i][lr]      = acc0[i];
                red[q][kc*4+i][16+lr]   = acc1[i];
            }
            int local = tid & 255;
            if(local < 64){   // ax cols 128..131 (16 rows x 4)
                int r = local>>2, f = local&3;
                Zs[r][128+f] = AXP16[(size_t)(m0+r)*1024 + t*32 + b*4 + f];
            }
            for(int idx = local; idx < 16*28; idx += 256){  // pad cols 132..159
                int r = idx/28, c2 = 132 + (idx - r*28);
                Zs[r][c2] = (f16)0.f;
            }
            if(t == 0){
                for(int idx = local; idx < 16*128; idx += 256)
                    Zs[idx>>7][idx&127] = (f16)0.f;
            }
        }
        __syncthreads();
        if(kh == 0 && t > 0){
            #pragma unroll
            for(int i=0;i<4;i++){
                int r = kc*4 + i;
                Zs[r][q*32 + lr]      = (f16)(acc0[i] + red[q][r][lr]);
                Zs[r][q*32 + 16 + lr] = (f16)(acc1[i] + red[q][r][16+lr]);
            }
        }
        __syncthreads();
    }

    // ---- act phase: 16 rows x 512 cols, wave w -> cols [w*64, w*64+64) ----
    {
        const int cbase = w*64;
        const f16* Bp2 = WzX16 + (size_t)(cbase + lr)*160 + kc*8;
        f32x4 acc[4] = {};
        #pragma unroll
        for(int k0=0; k0<160; k0+=32){
            half8 a = *(const half8*)&Zs[lr][kc*8 + k0];
            #pragma unroll
            for(int f=0; f<4; f++){
                half8 bb = *(const half8*)(Bp2 + (size_t)f*16*160 + k0);
                acc[f] = __builtin_amdgcn_mfma_f32_16x16x32_f16(a, bb, acc[f], 0,0,0);
            }
        }
        #pragma unroll
        for(int f=0; f<4; f++)
          #pragma unroll
          for(int i=0; i<4; i++){
            int m = m0 + kc*4 + i;
            int j = cbase + f*16 + lr;
            float v = acc[f][i] + bias512[j];
            act[(size_t)(m*8+b)*512 + j] = (j<384) ? sig_fast(v) : tanh_fast(v);
          }
    }
}

// ---------------- encoder pointwise: scramble -> hidT + ctx accum (XCD-aligned: bid%8 = b) ----------------
__global__ void kscr(const f32* __restrict__ act, f16* __restrict__ hidT,
                     f32* __restrict__ ctx)
{
    int blk = blockIdx.x;            // 512 blocks
    int b  = blk & 7;                // XCD-aligned with kfz's act writes for batch b
    int n0 = (blk >> 3) * 16;
    __shared__ f16 th[16][128];
    #pragma unroll
    for(int i=0;i<8;i++){
        int flat = i*256 + threadIdx.x;       // 0..2047
        int nl = flat >> 7, c = flat & 127;
        int n = n0 + nl;
        int p = n*128 + c;
        unsigned q1 = (unsigned)p + NH_, q2 = (unsigned)p + 2u*NH_;
        unsigned n1 = q1/384u, j1 = q1 - n1*384u;
        unsigned n2 = q2/384u, j2 = q2 - n2*384u;
        float ig = act[(size_t)(n1*8u + b)*512u + j1];
        float og = act[(size_t)(n2*8u + b)*512u + j2];
        float cs = act[(size_t)((unsigned)n*8u + b)*512u + 384u + c];
        float h = og * tanh_fast(ig*cs);
        ctx[((b<<10)|n)*128 + c] += h;
        th[nl][c] = (f16)h;
    }
    __syncthreads();
    int c_o = threadIdx.x >> 1, half = threadIdx.x & 1;
    half8 v;
    #pragma unroll
    for(int j=0;j<8;j++) v[j] = th[half*8+j][c_o];
    *(half8*)(hidT + (size_t)(b*128 + c_o)*1024 + n0 + half*8) = v;
}

// ---------------- zero ----------------
__global__ void kzero(f32* __restrict__ p, int n){
    int i = blockIdx.x*blockDim.x + threadIdx.x;
    int stride = gridDim.x*blockDim.x;
    for(; i<n; i+=stride) p[i] = 0.f;
}

// ---------------- fp32 tiled GEMM (ctxA only, runs once): C = ctx @ WihT + biasP ----------------
__global__ __launch_bounds__(256)
void gemmCtxA(const f32* __restrict__ A, const f32* __restrict__ Bm, f32* __restrict__ C,
              const f32* __restrict__ bias)
{
    __shared__ float As[16][68];
    __shared__ float Bs[16][64];
    const int tid = threadIdx.x;
    const int tx = tid & 15, ty = tid >> 4;
    const int col0 = blockIdx.x*64, row0 = blockIdx.y*64;
    const int am = tid >> 2, aq = tid & 3;
    const int bcol = tid & 63, bkr = tid >> 6;
    const int lda = 128, ldb = 512, Ncol = 512, K = 128;

    float acc[4][4] = {};
    for(int k0 = 0; k0 < K; k0 += 16){
        const float4 a4 = *(const float4*)(A + (size_t)(row0+am)*lda + k0 + aq*4);
        float bv[4];
        #pragma unroll
        for(int i=0;i<4;i++) bv[i] = Bm[(size_t)(k0 + bkr*4 + i)*ldb + col0 + bcol];
        #pragma unroll
        for(int i=0;i<4;i++) As[aq*4+i][am] = ((const float*)&a4)[i];
        #pragma unroll
        for(int i=0;i<4;i++) Bs[bkr*4+i][bcol] = bv[i];
        __syncthreads();
        #pragma unroll
        for(int kk=0;kk<16;kk++){
            float4 av  = *(const float4*)&As[kk][ty*4];
            float4 bvv = *(const float4*)&Bs[kk][tx*4];
            #pragma unroll
            for(int i=0;i<4;i++)
                #pragma unroll
                for(int j=0;j<4;j++)
                    acc[i][j] += ((const float*)&av)[i] * ((const float*)&bvv)[j];
        }
        __syncthreads();
    }
    #pragma unroll
    for(int i=0;i<4;i++){
        int r = row0 + ty*4 + i;
        #pragma unroll
        for(int j=0;j<4;j++){
            int cidx = col0 + tx*4 + j;
            C[(size_t)r*Ncol + cidx] = acc[i][j] + bias[cidx];
        }
    }
}

// ---------------- persistent decoder: 32 LSTM steps; Whh in registers; fast pointwise ----------------
__global__ __launch_bounds__(512)
void kdec(const f16* __restrict__ Whh16, const f32* __restrict__ ctxA,
          f32* __restrict__ out)
{
    const int lane = threadIdx.x & 63;
    const int w = threadIdx.x >> 6;
    const int r0 = blockIdx.x * 32;
    const int lr = lane & 15, kc = lane >> 4;
    const int cw = w*16 + lr;             // 0..127

    __shared__ f16 hx[32][152];
    {
        f16* hp = &hx[0][0];
        for(int i = threadIdx.x; i < 32*152; i += 512) hp[i] = (f16)0.f;
    }

    half8 wreg[4][4];
    #pragma unroll
    for(int kk=0; kk<4; ++kk)
      #pragma unroll
      for(int g=0; g<4; ++g)
        wreg[kk][g] = *(const half8*)(Whh16 + (size_t)(g*128 + cw)*128 + kc*8 + kk*32);

    float ca[2][4][4];
    float cxr[2][4];
    #pragma unroll
    for(int a=0;a<2;a++)
      #pragma unroll
      for(int i=0;i<4;i++){
        int r = r0 + a*16 + kc*4 + i;
        #pragma unroll
        for(int g=0;g<4;g++)
            ca[a][g][i] = ctxA[(size_t)r*512 + g*128 + cw];
        cxr[a][i] = 0.f;
      }
    __syncthreads();

    for(int s=0; s<32; ++s){
        f32x4 acc[2][4] = {};
        #pragma unroll
        for(int kk=0; kk<4; ++kk){
            half8 a0 = *(const half8*)&hx[lr][kc*8 + kk*32];
            half8 a1 = *(const half8*)&hx[16+lr][kc*8 + kk*32];
            #pragma unroll
            for(int g=0; g<4; ++g){
                acc[0][g] = __builtin_amdgcn_mfma_f32_16x16x32_f16(a0, wreg[kk][g], acc[0][g], 0,0,0);
                acc[1][g] = __builtin_amdgcn_mfma_f32_16x16x32_f16(a1, wreg[kk][g], acc[1][g], 0,0,0);
            }
        }
        __syncthreads();   // all hx reads done before overwrite
        #pragma unroll
        for(int a=0;a<2;a++)
          #pragma unroll
          for(int i=0;i<4;i++){
            float ig = sig_fast (acc[a][0][i] + ca[a][0][i]);
            float fg = sig_fast (acc[a][1][i] + ca[a][1][i]);
            float gg = tanh_fast(acc[a][2][i] + ca[a][2][i]);
            float og = sig_fast (acc[a][3][i] + ca[a][3][i]);
            float cv = fg*cxr[a][i] + ig*gg;
            cxr[a][i] = cv;
            float h = og*tanh_fast(cv);
            int rloc = a*16 + kc*4 + i;
            hx[rloc][cw] = (f16)h;
            if(s==31) out[(size_t)(r0 + rloc)*128 + cw] = h;
          }
        __syncthreads();
    }
}

extern "C" void kernel_launch(void* const* d_in, const int* in_sizes, int n_in,
                              void* d_out, int out_size, void* d_ws, size_t ws_size,
                              hipStream_t stream) {
    const f32* x   = (const f32*)d_in[0];
    const f32* adj = (const f32*)d_in[1];
    const f32* W1  = (const f32*)d_in[2];
    const f32* b1  = (const f32*)d_in[3];
    const f32* W2  = (const f32*)d_in[4];
    const f32* b2  = (const f32*)d_in[5];
    const f32* Wih = (const f32*)d_in[6];
    const f32* Whh = (const f32*)d_in[7];
    const f32* bih = (const f32*)d_in[8];
    const f32* bhh = (const f32*)d_in[9];
    f32* out = (f32*)d_out;
    f32* ws  = (f32*)d_ws;

    // workspace layout, f32 units — IDENTICAL to rounds 5-12 (verified).
    f32* ctx    = ws;                         // [0,        1048576)
    f16* hidT   = (f16*)(ws + 1048576);       // [1048576,  1572864)
    // gap (old Zp region, unused)
    f32* act    = ws + 2228224;               // [2228224,  6422528)
    f32* ctxA   = ws + 6422528;               // [6422528, 10616832)
    f16* AXP16  = (f16*)(ws + 10616832);      // [10616832, 11141120)
    f16* XrT    = (f16*)(ws + 11141120);      // [11141120, 11665408)
    f16* adj16  = (f16*)(ws + 11665408);      // [11665408, 12189696)
    f16* WzX16  = (f16*)(ws + 12189696);      // [12189696, 12230656)
    f16* Whh16  = (f16*)(ws + 12230656);      // [12230656, 12263424)
    f32* WihT   = ws + 12263424;              // [12263424, 12328960)
    f32* bias512= ws + 12328960;              // [12328960, 12329472)
    f32* biasP  = ws + 12329472;              // [12329472, 12329984)
    // end: 12329984 f32 = 49.3 MB

    const int TPB = 256;
    // zero: ctx + hidT
    hipLaunchKernelGGL(kzero, dim3(2048), dim3(TPB), 0, stream, ws, 1572864);
    hipLaunchKernelGGL(kprep, dim3(4096), dim3(TPB), 0, stream,
                       adj, x, W1,b1,W2,b2, Wih,Whh,bih,bhh,
                       adj16, XrT, WzX16, Whh16, WihT, bias512, biasP);

    // AXP16 = adj @ Xr (flat f16 out)
    hipLaunchKernelGGL(kbigAXP, dim3(32,32), dim3(TPB), 0, stream, adj16, XrT, AXP16);

    // encoder: fused (Z in LDS + act, 2 blocks/CU) + XCD-aligned scramble
    for(int t = 0; t < S_; ++t){
        hipLaunchKernelGGL(kfz, dim3(512), dim3(512), 0, stream,
                           adj16, hidT, WzX16, AXP16, bias512, act, t);
        hipLaunchKernelGGL(kscr, dim3(512), dim3(TPB), 0, stream, act, hidT, ctx);
    }

    // ctxA = ctx @ WihT + (b_ih + b_hh)
    hipLaunchKernelGGL(gemmCtxA, dim3(8,128), dim3(TPB), 0, stream, ctx, WihT, ctxA, biasP);

    // decoder: one persistent kernel, 32 steps, rows independent
    hipLaunchKernelGGL(kdec, dim3(256), dim3(512), 0, stream, Whh16, ctxA, out);
}

// Round 14
// 1026.021 us; speedup vs baseline: 1.2327x; 1.2327x over previous
//
#include <hip/hip_runtime.h>
#include <hip/hip_bf16.h>

#define B_   8
#define S_   32
#define N_   1024
#define H_   128
#define NH_  131072u    // N_*H_

typedef float f32;
typedef _Float16 f16;
typedef _Float16 half8 __attribute__((ext_vector_type(8)));
typedef float f32x4 __attribute__((ext_vector_type(4)));
typedef float f32x16 __attribute__((ext_vector_type(16)));

__device__ __forceinline__ float sig_fast(float x){
    return __builtin_amdgcn_rcpf(1.0f + __expf(-x));
}
__device__ __forceinline__ float tanh_fast(float x){
    return 1.0f - 2.0f*__builtin_amdgcn_rcpf(1.0f + __expf(2.0f*x));
}

// ---------------- weight prep + x transpose + ctx/hidT zero (merged) ----------------
__global__ void kprep(const f32* __restrict__ adj, const f32* __restrict__ x,
                      const f32* __restrict__ W1, const f32* __restrict__ b1,
                      const f32* __restrict__ W2, const f32* __restrict__ b2,
                      const f32* __restrict__ Wih, const f32* __restrict__ Whh,
                      const f32* __restrict__ bih, const f32* __restrict__ bhh,
                      f16* __restrict__ adj16, f16* __restrict__ XrT,
                      f16* __restrict__ WzX16, f16* __restrict__ Whh16,
                      f32* __restrict__ WihT, f32* __restrict__ bias512,
                      f32* __restrict__ biasP, f32* __restrict__ zero0,
                      f32* __restrict__ zero1)
{
    int i = blockIdx.x*blockDim.x + threadIdx.x;
    if(i < 1048576){
        adj16[i] = (f16)adj[i];
        int m = i & 1023, q = i >> 10;
        int f = q & 3, b = (q>>2)&7, t = q>>5;
        XrT[i] = (f16)x[((b*32+t)<<12) + (m<<2) + f];
        zero0[i] = 0.f;                 // ctx
    }
    if(i < 524288) zero1[i] = 0.f;      // hidT (f32 slots)
    if(i < 81920){
        int j = i/160, k = i - j*160;
        float v;
        if(k < 128)      v = (j<384) ? W1[(4+k)*384 + j] : W2[(4+k)*128 + (j-384)];
        else if(k < 132) v = (j<384) ? W1[(k-128)*384 + j] : W2[(k-128)*128 + (j-384)];
        else             v = 0.f;
        WzX16[i] = (f16)v;
    }
    if(i < 65536){
        Whh16[i] = (f16)Whh[i];
        int k = i>>9, jj = i&511;
        WihT[i] = Wih[jj*128 + k];
    }
    if(i < 512){
        bias512[i] = (i<384) ? b1[i] : b2[i-384];
        biasP[i]   = bih[i] + bhh[i];
    }
}

// ---------------- AXP GEMM (runs once): C(1024x1024) = adj16 @ XrT^T, flat f16 out ----------------
__global__ __launch_bounds__(256, 4)
void kbigAXP(const f16* __restrict__ A, const f16* __restrict__ Bt, f16* __restrict__ C)
{
    const int lane = threadIdx.x & 63;
    const int w = threadIdx.x >> 6;          // k-quarter
    const int row0 = blockIdx.y*32, col0 = blockIdx.x*32;

    const int mr = row0 + (lane & 31);
    const int nc = col0 + (lane & 31);
    const int kb = w*256 + (lane>>5)*8;
    const f16* Ap = A  + (size_t)mr*1024 + kb;
    const f16* Bp = Bt + (size_t)nc*1024 + kb;

    half8 Ab[8], Bb[8];
    #pragma unroll
    for(int i=0;i<8;i++){
        Ab[i] = *(const half8*)(Ap + i*16);
        Bb[i] = *(const half8*)(Bp + i*16);
    }
    f32x16 acc0 = {}, acc1 = {};
    #pragma unroll
    for(int it=0; it<16; ++it){
        half8 av = Ab[it&7], bv = Bb[it&7];
        if(it < 8){
            Ab[it] = *(const half8*)(Ap + (it+8)*16);
            Bb[it] = *(const half8*)(Bp + (it+8)*16);
        }
        if(it & 1) acc1 = __builtin_amdgcn_mfma_f32_32x32x16_f16(av, bv, acc1, 0,0,0);
        else       acc0 = __builtin_amdgcn_mfma_f32_32x32x16_f16(av, bv, acc0, 0,0,0);
    }
    f32x16 acc = acc0 + acc1;

    __shared__ float red[3][32][32];
    if(w > 0){
        #pragma unroll
        for(int i=0;i<16;i++){
            int r = (i&3) + 8*(i>>2) + 4*(lane>>5);
            red[w-1][r][lane&31] = acc[i];
        }
    }
    __syncthreads();
    if(w == 0){
        #pragma unroll
        for(int i=0;i<16;i++){
            int r = (i&3) + 8*(i>>2) + 4*(lane>>5);
            int c = lane & 31;
            float v = acc[i] + red[0][r][c] + red[1][r][c] + red[2][r][c];
            C[(size_t)(row0 + r)*1024 + col0 + c] = (f16)v;
        }
    }
}

// ---------------- fused encoder step GEMM: Z (LDS) + act   [R12-proven geometry] ----------------
// grid (8 b, 32 mg), 512 thr = 8 waves. Per block: nodes m0..m0+31, batch b. bid%8==b -> XCD b.
__global__ __launch_bounds__(512)
void kfz(const f16* __restrict__ adj16, const f16* __restrict__ hidT,
         const f16* __restrict__ WzX16, const f16* __restrict__ AXP16,
         const f32* __restrict__ bias512, f32* __restrict__ act, int t)
{
    const int tid = threadIdx.x;
    const int lane = tid & 63;
    const int w = tid >> 6;
    const int q = w & 3, kh = w >> 2;
    const int b = blockIdx.x;          // 0..7
    const int m0 = blockIdx.y * 32;    // node group

    __shared__ float red[4][32][32];   // 16 KB
    __shared__ f16 Zs[32][160];        // 10 KB

    {   // ---- Z phase ----
        f32x16 acc0 = {}, acc1 = {};
        if(t > 0){
            const int mr = m0 + (lane & 31);
            const int nc = b*128 + q*32 + (lane & 31);
            const int kb = kh*512 + (lane>>5)*8;
            const f16* Ap = adj16 + (size_t)mr*1024 + kb;
            const f16* Bp = hidT  + (size_t)nc*1024 + kb;

            half8 Ab[8], Bb[8];
            #pragma unroll
            for(int i=0;i<8;i++){
                Ab[i] = *(const half8*)(Ap + i*16);
                Bb[i] = *(const half8*)(Bp + i*16);
            }
            #pragma unroll
            for(int it=0; it<32; ++it){
                half8 av = Ab[it&7], bv = Bb[it&7];
                if(it < 24){
                    Ab[it&7] = *(const half8*)(Ap + (it+8)*16);
                    Bb[it&7] = *(const half8*)(Bp + (it+8)*16);
                }
                if(it & 1) acc1 = __builtin_amdgcn_mfma_f32_32x32x16_f16(av, bv, acc1, 0,0,0);
                else       acc0 = __builtin_amdgcn_mfma_f32_32x32x16_f16(av, bv, acc0, 0,0,0);
            }
        }
        f32x16 acc = acc0 + acc1;

        if(kh == 1){
            #pragma unroll
            for(int i=0;i<16;i++){
                int r = (i&3) + 8*(i>>2) + 4*(lane>>5);
                red[q][r][lane&31] = acc[i];
            }
            int local = tid & 255;
            if(local < 128){   // ax cols 128..131
                int m = local>>2, f = local&3;
                Zs[m][128+f] = AXP16[(size_t)(m0+m)*1024 + t*32 + b*4 + f];
            }
            for(int idx = local; idx < 32*28; idx += 256){  // pad cols 132..159
                int r = idx/28, c2 = 132 + (idx - r*28);
                Zs[r][c2] = (f16)0.f;
            }
        }
        __syncthreads();
        if(kh == 0){
            #pragma unroll
            for(int i=0;i<16;i++){
                int r = (i&3) + 8*(i>>2) + 4*(lane>>5);
                int c = lane & 31;
                Zs[r][q*32 + c] = (f16)(acc[i] + red[q][r][c]);
            }
        }
        __syncthreads();
    }

    // ---- act phase ----
    {
        const int lr = lane & 15, kc = lane >> 4;
        const int cbase = w*64;
        const f16* Bp2 = WzX16 + (size_t)(cbase + lr)*160 + kc*8;
        f32x4 acc2[2][4] = {};
        #pragma unroll
        for(int k0=0; k0<160; k0+=32){
            half8 a0 = *(const half8*)&Zs[lr][kc*8 + k0];
            half8 a1 = *(const half8*)&Zs[16+lr][kc*8 + k0];
            #pragma unroll
            for(int f=0; f<4; f++){
                half8 bb = *(const half8*)(Bp2 + (size_t)f*16*160 + k0);
                acc2[0][f] = __builtin_amdgcn_mfma_f32_16x16x32_f16(a0, bb, acc2[0][f], 0,0,0);
                acc2[1][f] = __builtin_amdgcn_mfma_f32_16x16x32_f16(a1, bb, acc2[1][f], 0,0,0);
            }
        }
        #pragma unroll
        for(int a=0;a<2;a++)
          #pragma unroll
          for(int f=0; f<4; f++)
            #pragma unroll
            for(int i=0; i<4; i++){
                int m = m0 + a*16 + kc*4 + i;
                int j = cbase + f*16 + lr;
                float v = acc2[a][f][i] + bias512[j];
                act[(size_t)(m*8+b)*512 + j] = (j<384) ? sig_fast(v) : tanh_fast(v);
            }
    }
}

// ---------------- encoder pointwise: scramble -> hidT + ctx accum (XCD-aligned: bid%8 = b) ----------------
__global__ void kscr(const f32* __restrict__ act, f16* __restrict__ hidT,
                     f32* __restrict__ ctx)
{
    int blk = blockIdx.x;            // 512 blocks
    int b  = blk & 7;                // XCD-aligned with kfz's act writes for batch b
    int n0 = (blk >> 3) * 16;
    __shared__ f16 th[16][128];
    #pragma unroll
    for(int i=0;i<8;i++){
        int flat = i*256 + threadIdx.x;       // 0..2047
        int nl = flat >> 7, c = flat & 127;
        int n = n0 + nl;
        int p = n*128 + c;
        unsigned q1 = (unsigned)p + NH_, q2 = (unsigned)p + 2u*NH_;
        unsigned n1 = q1/384u, j1 = q1 - n1*384u;
        unsigned n2 = q2/384u, j2 = q2 - n2*384u;
        float ig = act[(size_t)(n1*8u + b)*512u + j1];
        float og = act[(size_t)(n2*8u + b)*512u + j2];
        float cs = act[(size_t)((unsigned)n*8u + b)*512u + 384u + c];
        float h = og * tanh_fast(ig*cs);
        ctx[((b<<10)|n)*128 + c] += h;
        th[nl][c] = (f16)h;
    }
    __syncthreads();
    int c_o = threadIdx.x >> 1, half = threadIdx.x & 1;
    half8 v;
    #pragma unroll
    for(int j=0;j<8;j++) v[j] = th[half*8+j][c_o];
    *(half8*)(hidT + (size_t)(b*128 + c_o)*1024 + n0 + half*8) = v;
}

// ---------------- fp32 tiled GEMM (ctxA only, runs once): C = ctx @ WihT + biasP ----------------
__global__ __launch_bounds__(256)
void gemmCtxA(const f32* __restrict__ A, const f32* __restrict__ Bm, f32* __restrict__ C,
              const f32* __restrict__ bias)
{
    __shared__ float As[16][68];
    __shared__ float Bs[16][64];
    const int tid = threadIdx.x;
    const int tx = tid & 15, ty = tid >> 4;
    const int col0 = blockIdx.x*64, row0 = blockIdx.y*64;
    const int am = tid >> 2, aq = tid & 3;
    const int bcol = tid & 63, bkr = tid >> 6;
    const int lda = 128, ldb = 512, Ncol = 512, K = 128;

    float acc[4][4] = {};
    for(int k0 = 0; k0 < K; k0 += 16){
        const float4 a4 = *(const float4*)(A + (size_t)(row0+am)*lda + k0 + aq*4);
        float bv[4];
        #pragma unroll
        for(int i=0;i<4;i++) bv[i] = Bm[(size_t)(k0 + bkr*4 + i)*ldb + col0 + bcol];
        #pragma unroll
        for(int i=0;i<4;i++) As[aq*4+i][am] = ((const float*)&a4)[i];
        #pragma unroll
        for(int i=0;i<4;i++) Bs[bkr*4+i][bcol] = bv[i];
        __syncthreads();
        #pragma unroll
        for(int kk=0;kk<16;kk++){
            float4 av  = *(const float4*)&As[kk][ty*4];
            float4 bvv = *(const float4*)&Bs[kk][tx*4];
            #pragma unroll
            for(int i=0;i<4;i++)
                #pragma unroll
                for(int j=0;j<4;j++)
                    acc[i][j] += ((const float*)&av)[i] * ((const float*)&bvv)[j];
        }
        __syncthreads();
    }
    #pragma unroll
    for(int i=0;i<4;i++){
        int r = row0 + ty*4 + i;
        #pragma unroll
        for(int j=0;j<4;j++){
            int cidx = col0 + tx*4 + j;
            C[(size_t)r*Ncol + cidx] = acc[i][j] + bias[cidx];
        }
    }
}

// ---------------- persistent decoder v2: 512 blocks x 512 thr, 16 rows/block, 2 blocks/CU ----------------
__global__ __launch_bounds__(512, 4)
void kdec(const f16* __restrict__ Whh16, const f32* __restrict__ ctxA,
          f32* __restrict__ out)
{
    const int lane = threadIdx.x & 63;
    const int w = threadIdx.x >> 6;
    const int r0 = blockIdx.x * 16;
    const int lr = lane & 15, kc = lane >> 4;
    const int cw = w*16 + lr;             // 0..127

    __shared__ f16 hx[16][152];
    {
        f16* hp = &hx[0][0];
        for(int i = threadIdx.x; i < 16*152; i += 512) hp[i] = (f16)0.f;
    }

    half8 wreg[4][4];
    #pragma unroll
    for(int kk=0; kk<4; ++kk)
      #pragma unroll
      for(int g=0; g<4; ++g)
        wreg[kk][g] = *(const half8*)(Whh16 + (size_t)(g*128 + cw)*128 + kc*8 + kk*32);

    float ca[4][4];
    float cxr[4];
    #pragma unroll
    for(int i=0;i<4;i++){
        int r = r0 + kc*4 + i;
        #pragma unroll
        for(int g=0;g<4;g++)
            ca[g][i] = ctxA[(size_t)r*512 + g*128 + cw];
        cxr[i] = 0.f;
    }
    __syncthreads();

    for(int s=0; s<32; ++s){
        f32x4 acc[4] = {};
        #pragma unroll
        for(int kk=0; kk<4; ++kk){
            half8 a0 = *(const half8*)&hx[lr][kc*8 + kk*32];
            #pragma unroll
            for(int g=0; g<4; ++g)
                acc[g] = __builtin_amdgcn_mfma_f32_16x16x32_f16(a0, wreg[kk][g], acc[g], 0,0,0);
        }
        __syncthreads();   // all hx reads done before overwrite
        #pragma unroll
        for(int i=0;i<4;i++){
            float ig = sig_fast (acc[0][i] + ca[0][i]);
            float fg = sig_fast (acc[1][i] + ca[1][i]);
            float gg = tanh_fast(acc[2][i] + ca[2][i]);
            float og = sig_fast (acc[3][i] + ca[3][i]);
            float cv = fg*cxr[i] + ig*gg;
            cxr[i] = cv;
            float h = og*tanh_fast(cv);
            int rloc = kc*4 + i;
            hx[rloc][cw] = (f16)h;
            if(s==31) out[(size_t)(r0 + rloc)*128 + cw] = h;
        }
        __syncthreads();
    }
}

extern "C" void kernel_launch(void* const* d_in, const int* in_sizes, int n_in,
                              void* d_out, int out_size, void* d_ws, size_t ws_size,
                              hipStream_t stream) {
    const f32* x   = (const f32*)d_in[0];
    const f32* adj = (const f32*)d_in[1];
    const f32* W1  = (const f32*)d_in[2];
    const f32* b1  = (const f32*)d_in[3];
    const f32* W2  = (const f32*)d_in[4];
    const f32* b2  = (const f32*)d_in[5];
    const f32* Wih = (const f32*)d_in[6];
    const f32* Whh = (const f32*)d_in[7];
    const f32* bih = (const f32*)d_in[8];
    const f32* bhh = (const f32*)d_in[9];
    f32* out = (f32*)d_out;
    f32* ws  = (f32*)d_ws;

    // workspace layout, f32 units — IDENTICAL to rounds 5-13 (verified).
    f32* ctx    = ws;                         // [0,        1048576)
    f16* hidT   = (f16*)(ws + 1048576);       // [1048576,  1572864)
    // gap (old Zp region, unused)
    f32* act    = ws + 2228224;               // [2228224,  6422528)
    f32* ctxA   = ws + 6422528;               // [6422528, 10616832)
    f16* AXP16  = (f16*)(ws + 10616832);      // [10616832, 11141120)
    f16* XrT    = (f16*)(ws + 11141120);      // [11141120, 11665408)
    f16* adj16  = (f16*)(ws + 11665408);      // [11665408, 12189696)
    f16* WzX16  = (f16*)(ws + 12189696);      // [12189696, 12230656)
    f16* Whh16  = (f16*)(ws + 12230656);      // [12230656, 12263424)
    f32* WihT   = ws + 12263424;              // [12263424, 12328960)
    f32* bias512= ws + 12328960;              // [12328960, 12329472)
    f32* biasP  = ws + 12329472;              // [12329472, 12329984)
    // end: 12329984 f32 = 49.3 MB

    const int TPB = 256;
    hipLaunchKernelGGL(kprep, dim3(4096), dim3(TPB), 0, stream,
                       adj, x, W1,b1,W2,b2, Wih,Whh,bih,bhh,
                       adj16, XrT, WzX16, Whh16, WihT, bias512, biasP,
                       ctx, (f32*)hidT);

    // AXP16 = adj @ Xr (flat f16 out)
    hipLaunchKernelGGL(kbigAXP, dim3(32,32), dim3(TPB), 0, stream, adj16, XrT, AXP16);

    // encoder: fused (Z in LDS + act) + XCD-aligned scramble
    for(int t = 0; t < S_; ++t){
        hipLaunchKernelGGL(kfz, dim3(8,32), dim3(512), 0, stream,
                           adj16, hidT, WzX16, AXP16, bias512, act, t);
        hipLaunchKernelGGL(kscr, dim3(512), dim3(TPB), 0, stream, act, hidT, ctx);
    }

    // ctxA = ctx @ WihT + (b_ih + b_hh)
    hipLaunchKernelGGL(gemmCtxA, dim3(8,128), dim3(TPB), 0, stream, ctx, WihT, ctxA, biasP);

    // decoder: one persistent kernel, 32 steps, 16 rows/block, 2 blocks/CU
    hipLaunchKernelGGL(kdec, dim3(512), dim3(512), 0, stream, Whh16, ctxA, out);
}

// Round 15
// 1024.553 us; speedup vs baseline: 1.2345x; 1.0014x over previous
//
#include <hip/hip_runtime.h>
#include <hip/hip_bf16.h>

#define B_   8
#define S_   32
#define N_   1024
#define H_   128
#define NH_  131072u    // N_*H_

typedef float f32;
typedef _Float16 f16;
typedef _Float16 half8 __attribute__((ext_vector_type(8)));
typedef float f32x4 __attribute__((ext_vector_type(4)));
typedef float f32x16 __attribute__((ext_vector_type(16)));

__device__ __forceinline__ float sig_fast(float x){
    return __builtin_amdgcn_rcpf(1.0f + __expf(-x));
}
__device__ __forceinline__ float tanh_fast(float x){
    return 1.0f - 2.0f*__builtin_amdgcn_rcpf(1.0f + __expf(2.0f*x));
}

// ---------------- weight prep + x transpose + ctx/hidT zero (merged) ----------------
__global__ void kprep(const f32* __restrict__ adj, const f32* __restrict__ x,
                      const f32* __restrict__ W1, const f32* __restrict__ b1,
                      const f32* __restrict__ W2, const f32* __restrict__ b2,
                      const f32* __restrict__ Wih, const f32* __restrict__ Whh,
                      const f32* __restrict__ bih, const f32* __restrict__ bhh,
                      f16* __restrict__ adj16, f16* __restrict__ XrT,
                      f16* __restrict__ WzX16, f16* __restrict__ Whh16,
                      f32* __restrict__ WihT, f32* __restrict__ bias512,
                      f32* __restrict__ biasP, f32* __restrict__ zero0,
                      f32* __restrict__ zero1)
{
    int i = blockIdx.x*blockDim.x + threadIdx.x;
    if(i < 1048576){
        adj16[i] = (f16)adj[i];
        int m = i & 1023, q = i >> 10;
        int f = q & 3, b = (q>>2)&7, t = q>>5;
        XrT[i] = (f16)x[((b*32+t)<<12) + (m<<2) + f];
        zero0[i] = 0.f;                 // ctx
    }
    if(i < 524288) zero1[i] = 0.f;      // hidT (f32 slots)
    if(i < 81920){
        int j = i/160, k = i - j*160;
        float v;
        if(k < 128)      v = (j<384) ? W1[(4+k)*384 + j] : W2[(4+k)*128 + (j-384)];
        else if(k < 132) v = (j<384) ? W1[(k-128)*384 + j] : W2[(k-128)*128 + (j-384)];
        else             v = 0.f;
        WzX16[i] = (f16)v;
    }
    if(i < 65536){
        Whh16[i] = (f16)Whh[i];
        int k = i>>9, jj = i&511;
        WihT[i] = Wih[jj*128 + k];
    }
    if(i < 512){
        bias512[i] = (i<384) ? b1[i] : b2[i-384];
        biasP[i]   = bih[i] + bhh[i];
    }
}

// ---------------- AXP GEMM (runs once): C(1024x1024) = adj16 @ XrT^T, flat f16 out ----------------
__global__ __launch_bounds__(256, 4)
void kbigAXP(const f16* __restrict__ A, const f16* __restrict__ Bt, f16* __restrict__ C)
{
    const int lane = threadIdx.x & 63;
    const int w = threadIdx.x >> 6;          // k-quarter
    const int row0 = blockIdx.y*32, col0 = blockIdx.x*32;

    const int mr = row0 + (lane & 31);
    const int nc = col0 + (lane & 31);
    const int kb = w*256 + (lane>>5)*8;
    const f16* Ap = A  + (size_t)mr*1024 + kb;
    const f16* Bp = Bt + (size_t)nc*1024 + kb;

    half8 Ab[8], Bb[8];
    #pragma unroll
    for(int i=0;i<8;i++){
        Ab[i] = *(const half8*)(Ap + i*16);
        Bb[i] = *(const half8*)(Bp + i*16);
    }
    f32x16 acc0 = {}, acc1 = {};
    #pragma unroll
    for(int it=0; it<16; ++it){
        half8 av = Ab[it&7], bv = Bb[it&7];
        if(it < 8){
            Ab[it] = *(const half8*)(Ap + (it+8)*16);
            Bb[it] = *(const half8*)(Bp + (it+8)*16);
        }
        if(it & 1) acc1 = __builtin_amdgcn_mfma_f32_32x32x16_f16(av, bv, acc1, 0,0,0);
        else       acc0 = __builtin_amdgcn_mfma_f32_32x32x16_f16(av, bv, acc0, 0,0,0);
    }
    f32x16 acc = acc0 + acc1;

    __shared__ float red[3][32][32];
    if(w > 0){
        #pragma unroll
        for(int i=0;i<16;i++){
            int r = (i&3) + 8*(i>>2) + 4*(lane>>5);
            red[w-1][r][lane&31] = acc[i];
        }
    }
    __syncthreads();
    if(w == 0){
        #pragma unroll
        for(int i=0;i<16;i++){
            int r = (i&3) + 8*(i>>2) + 4*(lane>>5);
            int c = lane & 31;
            float v = acc[i] + red[0][r][c] + red[1][r][c] + red[2][r][c];
            C[(size_t)(row0 + r)*1024 + col0 + c] = (f16)v;
        }
    }
}

// ---------------- fused encoder step GEMM: Z (LDS) + act  [R12 geometry + depth-16 prefetch] ----------------
// grid (8 b, 32 mg), 512 thr = 8 waves. Per block: nodes m0..m0+31, batch b. bid%8==b -> XCD b.
__global__ __launch_bounds__(512)
void kfz(const f16* __restrict__ adj16, const f16* __restrict__ hidT,
         const f16* __restrict__ WzX16, const f16* __restrict__ AXP16,
         const f32* __restrict__ bias512, f32* __restrict__ act, int t)
{
    const int tid = threadIdx.x;
    const int lane = tid & 63;
    const int w = tid >> 6;
    const int q = w & 3, kh = w >> 2;
    const int b = blockIdx.x;          // 0..7
    const int m0 = blockIdx.y * 32;    // node group

    __shared__ float red[4][32][32];   // 16 KB
    __shared__ f16 Zs[32][160];        // 10 KB

    {   // ---- Z phase: depth-16 register prefetch (32 loads in flight/wave) ----
        f32x16 acc0 = {}, acc1 = {};
        if(t > 0){
            const int mr = m0 + (lane & 31);
            const int nc = b*128 + q*32 + (lane & 31);
            const int kb = kh*512 + (lane>>5)*8;
            const f16* Ap = adj16 + (size_t)mr*1024 + kb;
            const f16* Bp = hidT  + (size_t)nc*1024 + kb;

            half8 Ab[16], Bb[16];
            #pragma unroll
            for(int i=0;i<16;i++){
                Ab[i] = *(const half8*)(Ap + i*16);
                Bb[i] = *(const half8*)(Bp + i*16);
            }
            #pragma unroll
            for(int it=0; it<32; ++it){
                half8 av = Ab[it&15], bv = Bb[it&15];
                if(it < 16){
                    Ab[it] = *(const half8*)(Ap + (it+16)*16);
                    Bb[it] = *(const half8*)(Bp + (it+16)*16);
                }
                if(it & 1) acc1 = __builtin_amdgcn_mfma_f32_32x32x16_f16(av, bv, acc1, 0,0,0);
                else       acc0 = __builtin_amdgcn_mfma_f32_32x32x16_f16(av, bv, acc0, 0,0,0);
            }
        }
        f32x16 acc = acc0 + acc1;

        if(kh == 1){
            #pragma unroll
            for(int i=0;i<16;i++){
                int r = (i&3) + 8*(i>>2) + 4*(lane>>5);
                red[q][r][lane&31] = acc[i];
            }
            int local = tid & 255;
            if(local < 128){   // ax cols 128..131
                int m = local>>2, f = local&3;
                Zs[m][128+f] = AXP16[(size_t)(m0+m)*1024 + t*32 + b*4 + f];
            }
            for(int idx = local; idx < 32*28; idx += 256){  // pad cols 132..159
                int r = idx/28, c2 = 132 + (idx - r*28);
                Zs[r][c2] = (f16)0.f;
            }
        }
        __syncthreads();
        if(kh == 0){
            #pragma unroll
            for(int i=0;i<16;i++){
                int r = (i&3) + 8*(i>>2) + 4*(lane>>5);
                int c = lane & 31;
                Zs[r][q*32 + c] = (f16)(acc[i] + red[q][r][c]);
            }
        }
        __syncthreads();
    }

    // ---- act phase ----
    {
        const int lr = lane & 15, kc = lane >> 4;
        const int cbase = w*64;
        const f16* Bp2 = WzX16 + (size_t)(cbase + lr)*160 + kc*8;
        f32x4 acc2[2][4] = {};
        #pragma unroll
        for(int k0=0; k0<160; k0+=32){
            half8 a0 = *(const half8*)&Zs[lr][kc*8 + k0];
            half8 a1 = *(const half8*)&Zs[16+lr][kc*8 + k0];
            #pragma unroll
            for(int f=0; f<4; f++){
                half8 bb = *(const half8*)(Bp2 + (size_t)f*16*160 + k0);
                acc2[0][f] = __builtin_amdgcn_mfma_f32_16x16x32_f16(a0, bb, acc2[0][f], 0,0,0);
                acc2[1][f] = __builtin_amdgcn_mfma_f32_16x16x32_f16(a1, bb, acc2[1][f], 0,0,0);
            }
        }
        #pragma unroll
        for(int a=0;a<2;a++)
          #pragma unroll
          for(int f=0; f<4; f++)
            #pragma unroll
            for(int i=0; i<4; i++){
                int m = m0 + a*16 + kc*4 + i;
                int j = cbase + f*16 + lr;
                float v = acc2[a][f][i] + bias512[j];
                act[(size_t)(m*8+b)*512 + j] = (j<384) ? sig_fast(v) : tanh_fast(v);
            }
    }
}

// ---------------- encoder pointwise: scramble -> hidT + ctx accum (XCD-aligned: bid%8 = b) ----------------
__global__ void kscr(const f32* __restrict__ act, f16* __restrict__ hidT,
                     f32* __restrict__ ctx)
{
    int blk = blockIdx.x;            // 512 blocks
    int b  = blk & 7;                // XCD-aligned with kfz's act writes for batch b
    int n0 = (blk >> 3) * 16;
    __shared__ f16 th[16][128];
    #pragma unroll
    for(int i=0;i<8;i++){
        int flat = i*256 + threadIdx.x;       // 0..2047
        int nl = flat >> 7, c = flat & 127;
        int n = n0 + nl;
        int p = n*128 + c;
        unsigned q1 = (unsigned)p + NH_, q2 = (unsigned)p + 2u*NH_;
        unsigned n1 = q1/384u, j1 = q1 - n1*384u;
        unsigned n2 = q2/384u, j2 = q2 - n2*384u;
        float ig = act[(size_t)(n1*8u + b)*512u + j1];
        float og = act[(size_t)(n2*8u + b)*512u + j2];
        float cs = act[(size_t)((unsigned)n*8u + b)*512u + 384u + c];
        float h = og * tanh_fast(ig*cs);
        ctx[((b<<10)|n)*128 + c] += h;
        th[nl][c] = (f16)h;
    }
    __syncthreads();
    int c_o = threadIdx.x >> 1, half = threadIdx.x & 1;
    half8 v;
    #pragma unroll
    for(int j=0;j<8;j++) v[j] = th[half*8+j][c_o];
    *(half8*)(hidT + (size_t)(b*128 + c_o)*1024 + n0 + half*8) = v;
}

// ---------------- fp32 tiled GEMM (ctxA only, runs once): C = ctx @ WihT + biasP ----------------
__global__ __launch_bounds__(256)
void gemmCtxA(const f32* __restrict__ A, const f32* __restrict__ Bm, f32* __restrict__ C,
              const f32* __restrict__ bias)
{
    __shared__ float As[16][68];
    __shared__ float Bs[16][64];
    const int tid = threadIdx.x;
    const int tx = tid & 15, ty = tid >> 4;
    const int col0 = blockIdx.x*64, row0 = blockIdx.y*64;
    const int am = tid >> 2, aq = tid & 3;
    const int bcol = tid & 63, bkr = tid >> 6;
    const int lda = 128, ldb = 512, Ncol = 512, K = 128;

    float acc[4][4] = {};
    for(int k0 = 0; k0 < K; k0 += 16){
        const float4 a4 = *(const float4*)(A + (size_t)(row0+am)*lda + k0 + aq*4);
        float bv[4];
        #pragma unroll
        for(int i=0;i<4;i++) bv[i] = Bm[(size_t)(k0 + bkr*4 + i)*ldb + col0 + bcol];
        #pragma unroll
        for(int i=0;i<4;i++) As[aq*4+i][am] = ((const float*)&a4)[i];
        #pragma unroll
        for(int i=0;i<4;i++) Bs[bkr*4+i][bcol] = bv[i];
        __syncthreads();
        #pragma unroll
        for(int kk=0;kk<16;kk++){
            float4 av  = *(const float4*)&As[kk][ty*4];
            float4 bvv = *(const float4*)&Bs[kk][tx*4];
            #pragma unroll
            for(int i=0;i<4;i++)
                #pragma unroll
                for(int j=0;j<4;j++)
                    acc[i][j] += ((const float*)&av)[i] * ((const float*)&bvv)[j];
        }
        __syncthreads();
    }
    #pragma unroll
    for(int i=0;i<4;i++){
        int r = row0 + ty*4 + i;
        #pragma unroll
        for(int j=0;j<4;j++){
            int cidx = col0 + tx*4 + j;
            C[(size_t)r*Ncol + cidx] = acc[i][j] + bias[cidx];
        }
    }
}

// ---------------- persistent decoder: 512 blocks x 512 thr, 16 rows/block, 2 blocks/CU ----------------
__global__ __launch_bounds__(512, 4)
void kdec(const f16* __restrict__ Whh16, const f32* __restrict__ ctxA,
          f32* __restrict__ out)
{
    const int lane = threadIdx.x & 63;
    const int w = threadIdx.x >> 6;
    const int r0 = blockIdx.x * 16;
    const int lr = lane & 15, kc = lane >> 4;
    const int cw = w*16 + lr;             // 0..127

    __shared__ f16 hx[16][152];
    {
        f16* hp = &hx[0][0];
        for(int i = threadIdx.x; i < 16*152; i += 512) hp[i] = (f16)0.f;
    }

    half8 wreg[4][4];
    #pragma unroll
    for(int kk=0; kk<4; ++kk)
      #pragma unroll
      for(int g=0; g<4; ++g)
        wreg[kk][g] = *(const half8*)(Whh16 + (size_t)(g*128 + cw)*128 + kc*8 + kk*32);

    float ca[4][4];
    float cxr[4];
    #pragma unroll
    for(int i=0;i<4;i++){
        int r = r0 + kc*4 + i;
        #pragma unroll
        for(int g=0;g<4;g++)
            ca[g][i] = ctxA[(size_t)r*512 + g*128 + cw];
        cxr[i] = 0.f;
    }
    __syncthreads();

    for(int s=0; s<32; ++s){
        f32x4 acc[4] = {};
        #pragma unroll
        for(int kk=0; kk<4; ++kk){
            half8 a0 = *(const half8*)&hx[lr][kc*8 + kk*32];
            #pragma unroll
            for(int g=0; g<4; ++g)
                acc[g] = __builtin_amdgcn_mfma_f32_16x16x32_f16(a0, wreg[kk][g], acc[g], 0,0,0);
        }
        __syncthreads();   // all hx reads done before overwrite
        #pragma unroll
        for(int i=0;i<4;i++){
            float ig = sig_fast (acc[0][i] + ca[0][i]);
            float fg = sig_fast (acc[1][i] + ca[1][i]);
            float gg = tanh_fast(acc[2][i] + ca[2][i]);
            float og = sig_fast (acc[3][i] + ca[3][i]);
            float cv = fg*cxr[i] + ig*gg;
            cxr[i] = cv;
            float h = og*tanh_fast(cv);
            int rloc = kc*4 + i;
            hx[rloc][cw] = (f16)h;
            if(s==31) out[(size_t)(r0 + rloc)*128 + cw] = h;
        }
        __syncthreads();
    }
}

extern "C" void kernel_launch(void* const* d_in, const int* in_sizes, int n_in,
                              void* d_out, int out_size, void* d_ws, size_t ws_size,
                              hipStream_t stream) {
    const f32* x   = (const f32*)d_in[0];
    const f32* adj = (const f32*)d_in[1];
    const f32* W1  = (const f32*)d_in[2];
    const f32* b1  = (const f32*)d_in[3];
    const f32* W2  = (const f32*)d_in[4];
    const f32* b2  = (const f32*)d_in[5];
    const f32* Wih = (const f32*)d_in[6];
    const f32* Whh = (const f32*)d_in[7];
    const f32* bih = (const f32*)d_in[8];
    const f32* bhh = (const f32*)d_in[9];
    f32* out = (f32*)d_out;
    f32* ws  = (f32*)d_ws;

    // workspace layout, f32 units — IDENTICAL to rounds 5-14 (verified).
    f32* ctx    = ws;                         // [0,        1048576)
    f16* hidT   = (f16*)(ws + 1048576);       // [1048576,  1572864)
    // gap (old Zp region, unused)
    f32* act    = ws + 2228224;               // [2228224,  6422528)
    f32* ctxA   = ws + 6422528;               // [6422528, 10616832)
    f16* AXP16  = (f16*)(ws + 10616832);      // [10616832, 11141120)
    f16* XrT    = (f16*)(ws + 11141120);      // [11141120, 11665408)
    f16* adj16  = (f16*)(ws + 11665408);      // [11665408, 12189696)
    f16* WzX16  = (f16*)(ws + 12189696);      // [12189696, 12230656)
    f16* Whh16  = (f16*)(ws + 12230656);      // [12230656, 12263424)
    f32* WihT   = ws + 12263424;              // [12263424, 12328960)
    f32* bias512= ws + 12328960;              // [12328960, 12329472)
    f32* biasP  = ws + 12329472;              // [12329472, 12329984)
    // end: 12329984 f32 = 49.3 MB

    const int TPB = 256;
    hipLaunchKernelGGL(kprep, dim3(4096), dim3(TPB), 0, stream,
                       adj, x, W1,b1,W2,b2, Wih,Whh,bih,bhh,
                       adj16, XrT, WzX16, Whh16, WihT, bias512, biasP,
                       ctx, (f32*)hidT);

    // AXP16 = adj @ Xr (flat f16 out)
    hipLaunchKernelGGL(kbigAXP, dim3(32,32), dim3(TPB), 0, stream, adj16, XrT, AXP16);

    // encoder: fused (Z in LDS + act, depth-16 prefetch) + XCD-aligned scramble
    for(int t = 0; t < S_; ++t){
        hipLaunchKernelGGL(kfz, dim3(8,32), dim3(512), 0, stream,
                           adj16, hidT, WzX16, AXP16, bias512, act, t);
        hipLaunchKernelGGL(kscr, dim3(512), dim3(TPB), 0, stream, act, hidT, ctx);
    }

    // ctxA = ctx @ WihT + (b_ih + b_hh)
    hipLaunchKernelGGL(gemmCtxA, dim3(8,128), dim3(TPB), 0, stream, ctx, WihT, ctxA, biasP);

    // decoder: one persistent kernel, 32 steps, 16 rows/block, 2 blocks/CU
    hipLaunchKernelGGL(kdec, dim3(512), dim3(512), 0, stream, Whh16, ctxA, out);
}